// Round 13
// baseline (383.044 us; speedup 1.0000x reference)
//
#include <hip/hip_runtime.h>
#include <hip/hip_cooperative_groups.h>

namespace cg = cooperative_groups;

#define NN 50000
#define DD 50
#define RR 64
#define BINS 2048                   // (rel, e&31) sub-bins
#define CAP 128                     // slots per bin (mean ~49; 11.5-sigma margin)
#define GPB 8                       // 16-edge groups per bin
#define NGS (BINS * GPB)            // 16384 groups
#define CAPN 24                     // per-node perm slots (in-degree ~Poisson(2))

// meta ints: bin cursors | node cursors | perm | int2 slots
#define BINCUR_OFF 0                                   // 2048
#define DCUR_OFF   2048                                // 50000
#define PERM_OFF   52048                               // 50000*24
#define SD_OFF     1252048                             // 2*BINS*CAP = 524288
#define META_INTS  1776336
#define WB_BYTE    ((size_t)META_INTS * 4)             // 7,105,344
#define HB_BYTE    (WB_BYTE + (size_t)RR * 64 * 64 * 2)
#define MSG_BYTE   (HB_BYTE + (size_t)NN * 64 * 2)
#define WS_NEED    (MSG_BYTE + (size_t)NGS * 16 * 64 * 2)  // ~47.6 MB

typedef __attribute__((ext_vector_type(8))) short bf16x8;
typedef __attribute__((ext_vector_type(4))) float f32x4;

__device__ __forceinline__ unsigned short f2b(float f) {   // f32 -> bf16 RNE
    unsigned u = __float_as_uint(f);
    u = (u + 0x7fffu + ((u >> 16) & 1u)) >> 16;
    return (unsigned short)u;
}

// ---- P0: zero cursors; wb[r][n][k] = bf16 W^T zero-padded 64x64; hb = bf16 h padded to 64 cols
__device__ __forceinline__ void phase_init(int tid, int nth, int* meta,
        unsigned short* wb, unsigned short* hb,
        const float* w, const float* h) {
    for (int j = tid; j < BINS + NN; j += nth) meta[j] = 0;
    for (int j = tid; j < RR * 64 * 64; j += nth) {
        int r = j >> 12, d = (j >> 6) & 63, n = j & 63;
        float v = (n < DD && d < DD) ? w[r * (DD * DD) + d * DD + n] : 0.f;
        wb[(r << 12) + (n << 6) + d] = f2b(v);
    }
    for (int j = tid; j < NN * 32; j += nth) {
        int n = j >> 5, cp = j & 31;
        unsigned pack = 0;
        if (cp < 25) {
            float2 q = *(const float2*)(h + (size_t)n * DD + cp * 2);
            pack = (unsigned)f2b(q.x) | ((unsigned)f2b(q.y) << 16);
        }
        *(unsigned*)(hb + ((size_t)n << 6) + cp * 2) = pack;
    }
}

// ---- P1: scatter edges into (rel, e&31) bins
__device__ __forceinline__ void phase_scatter(int tid, int nth,
        const int* src, const int* dst, const int* rel, int E, int* meta) {
    for (int e = tid; e < E; e += nth) {
        int sb = (rel[e] << 5) | (e & 31);
        int p = atomicAdd(&meta[BINCUR_OFF + sb], 1);
        if (p < CAP)                                // never fires at 11.5 sigma
            ((int2*)(meta + SD_OFF))[sb * CAP + p] = make_int2(src[e], dst[e]);
    }
}

// ---- P2: one 16-edge group -> 8x MFMA -> bf16 msg rows + perm append
__device__ __forceinline__ void phase_edge(int g, int lane,
        const unsigned short* hb, const unsigned short* wb,
        int* meta, unsigned short* msg) {
    int sb = g >> 3, gi = g & 7;
    int cnt = __builtin_amdgcn_readfirstlane(meta[BINCUR_OFF + sb]);
    if (cnt > CAP) cnt = CAP;
    int nv = cnt - gi * 16;
    if (nv <= 0) return;
    if (nv > 16) nv = 16;
    int r = sb >> 5;
    int base = sb * CAP + gi * 16;

    int sv0 = 0;
    if (lane < nv) {
        int2 sd = ((const int2*)(meta + SD_OFF))[base + lane];
        sv0 = sd.x;
        int pos = atomicAdd(&meta[DCUR_OFF + sd.y], 1);
        if (pos < CAPN)                             // P ~ 1e-18, guard anyway
            meta[PERM_OFF + sd.y * CAPN + pos] = (g << 4) + lane;
    }
    int sv = __shfl(sv0, lane & 15);                // src of A row (row = lane&15)
    int ch = lane >> 4;                             // k-chunk 0..3

    const unsigned short* hrow = hb + ((size_t)sv << 6) + (ch << 3);
    bf16x8 a0 = *(const bf16x8*)hrow;               // k = ch*8..+7
    bf16x8 a1 = *(const bf16x8*)(hrow + 32);        // k = 32+ch*8..+7 (zero-padded)

    const unsigned short* wr = wb + ((size_t)r << 12) + ((lane & 15) << 6) + (ch << 3);
    f32x4 c[4];
    #pragma unroll
    for (int t = 0; t < 4; ++t) c[t] = (f32x4){0.f, 0.f, 0.f, 0.f};
    #pragma unroll
    for (int t = 0; t < 4; ++t) {
        bf16x8 b0 = *(const bf16x8*)(wr + t * 1024);
        bf16x8 b1 = *(const bf16x8*)(wr + t * 1024 + 32);
        c[t] = __builtin_amdgcn_mfma_f32_16x16x32_bf16(a0, b0, c[t], 0, 0, 0);
        c[t] = __builtin_amdgcn_mfma_f32_16x16x32_bf16(a1, b1, c[t], 0, 0, 0);
    }

    // C layout (m89): col = t*16 + (lane&15), row = ch*4 + q
    int col0 = lane & 15;
    unsigned short* mb = msg + (size_t)((g << 4) + (ch << 2)) * 64;
    #pragma unroll
    for (int q = 0; q < 4; ++q)
        #pragma unroll
        for (int t = 0; t < 4; ++t)
            mb[q * 64 + t * 16 + col0] = f2b(c[t][q]);
}

// ---- P3: one node -> gather msg rows via perm, +bias, relu, store
__device__ __forceinline__ void phase_agg(int n, int lane,
        const unsigned short* msg, const int* meta, float bl, float* out) {
    int cnt = __builtin_amdgcn_readfirstlane(meta[DCUR_OFF + n]);
    if (cnt > CAPN) cnt = CAPN;
    float v = 0.f;
    const int4* pp = (const int4*)(meta + PERM_OFF + n * CAPN);
    int4 P0 = pp[0], P1 = pp[1];                    // covers deg<=8 (99.98%)
    int pj[8] = {P0.x, P0.y, P0.z, P0.w, P1.x, P1.y, P1.z, P1.w};
    #pragma unroll
    for (int j = 0; j < 8; ++j) {
        if (j < cnt) {
            unsigned short u = msg[(size_t)pj[j] * 64 + lane];
            v += __uint_as_float((unsigned)u << 16);
        }
    }
    #pragma unroll 1
    for (int j = 8; j < cnt; ++j) {                 // rare tail
        int p = meta[PERM_OFF + n * CAPN + j];
        unsigned short u = msg[(size_t)p * 64 + lane];
        v += __uint_as_float((unsigned)u << 16);
    }
    if (lane < DD) {
        float o = v + bl;
        out[(size_t)n * DD + lane] = o > 0.f ? o : 0.f;
    }
}

// ================= cooperative fused kernel =================
__global__ __launch_bounds__(256, 4) void fused_kernel(
        const float* __restrict__ h, const float* __restrict__ w,
        const float* __restrict__ bias,
        const int* __restrict__ src, const int* __restrict__ dst,
        const int* __restrict__ rel, int E,
        int* __restrict__ meta, unsigned short* __restrict__ wb,
        unsigned short* __restrict__ hb, unsigned short* __restrict__ msg,
        float* __restrict__ out) {
    cg::grid_group grid = cg::this_grid();
    const int nth  = gridDim.x * blockDim.x;
    const int tid  = blockIdx.x * blockDim.x + threadIdx.x;
    const int lane = threadIdx.x & 63;
    const int wave = tid >> 6, nw = nth >> 6;

    phase_init(tid, nth, meta, wb, hb, w, h);
    grid.sync();
    phase_scatter(tid, nth, src, dst, rel, E, meta);
    grid.sync();
    for (int g = wave; g < NGS; g += nw) phase_edge(g, lane, hb, wb, meta, msg);
    grid.sync();
    float bl = (lane < DD) ? bias[lane] : 0.f;
    for (int n = wave; n < NN; n += nw) phase_agg(n, lane, msg, meta, bl, out);
}

// ================= split-path kernels (same phases) =================
__global__ __launch_bounds__(256) void k_init(int* meta, unsigned short* wb,
        unsigned short* hb, const float* w, const float* h) {
    phase_init(blockIdx.x * 256 + threadIdx.x, gridDim.x * 256, meta, wb, hb, w, h);
}
__global__ void k_scatter(const int* src, const int* dst, const int* rel, int E, int* meta) {
    phase_scatter(blockIdx.x * blockDim.x + threadIdx.x, gridDim.x * blockDim.x,
                  src, dst, rel, E, meta);
}
__global__ __launch_bounds__(256) void k_edge(const unsigned short* hb,
        const unsigned short* wb, int* meta, unsigned short* msg) {
    int wave = (blockIdx.x << 2) + (threadIdx.x >> 6);
    int lane = threadIdx.x & 63;
    int nw = gridDim.x << 2;
    for (int g = wave; g < NGS; g += nw) phase_edge(g, lane, hb, wb, meta, msg);
}
__global__ __launch_bounds__(256) void k_agg(const unsigned short* msg, const int* meta,
        const float* bias, float* out) {
    int wave = (blockIdx.x << 2) + (threadIdx.x >> 6);
    int lane = threadIdx.x & 63;
    int nw = gridDim.x << 2;
    float bl = (lane < DD) ? bias[lane] : 0.f;
    for (int n = wave; n < NN; n += nw) phase_agg(n, lane, msg, meta, bl, out);
}

// ---------- tiny-ws fallback: round-1 style atomics ----------
__global__ void fb_edge_kernel(const float* __restrict__ h, const float* __restrict__ weight,
                               const int* __restrict__ src_idx, const int* __restrict__ dst_idx,
                               const int* __restrict__ rel_type, float* __restrict__ acc, int E) {
    int wave = (int)((blockIdx.x * blockDim.x + threadIdx.x) >> 6);
    int lane = threadIdx.x & 63;
    if (wave >= E) return;
    int s = src_idx[wave], r = rel_type[wave], dn = dst_idx[wave];
    const float* hs = h + (size_t)s * DD;
    const float* W  = weight + (size_t)r * DD * DD;
    if (lane < DD) {
        float m = 0.f;
        for (int d = 0; d < DD; ++d) m = fmaf(hs[d], W[d * DD + lane], m);
        atomicAdd(&acc[(size_t)dn * DD + lane], m);
    }
}
__global__ void fb_finalize_kernel(float* __restrict__ out, const float* __restrict__ bias, int total) {
    int i = blockIdx.x * blockDim.x + threadIdx.x;
    if (i < total) {
        float v = out[i] + bias[i % DD];
        out[i] = v > 0.f ? v : 0.f;
    }
}

extern "C" void kernel_launch(void* const* d_in, const int* in_sizes, int n_in,
                              void* d_out, int out_size, void* d_ws, size_t ws_size,
                              hipStream_t stream) {
    const float* h      = (const float*)d_in[0];
    const float* weight = (const float*)d_in[1];
    const float* bias   = (const float*)d_in[2];
    const int*   src    = (const int*)d_in[3];
    const int*   dst    = (const int*)d_in[4];
    const int*   rel    = (const int*)d_in[5];
    float* out = (float*)d_out;
    int E = in_sizes[3];

    if (ws_size >= WS_NEED) {
        int* meta = (int*)d_ws;
        unsigned short* wb  = (unsigned short*)((char*)d_ws + WB_BYTE);
        unsigned short* hb  = (unsigned short*)((char*)d_ws + HB_BYTE);
        unsigned short* msg = (unsigned short*)((char*)d_ws + MSG_BYTE);

        // Size the cooperative grid from the runtime's own occupancy model
        // (pure query, capture-safe, deterministic).
        int maxB = 0;
        hipError_t qe = hipOccupancyMaxActiveBlocksPerMultiprocessor(
                            &maxB, fused_kernel, 256, 0);
        int grid = 1024;
        if (qe == hipSuccess && maxB > 0) {
            int cap = maxB * 256;                 // 256 CUs on MI355X
            if (cap < grid) grid = cap;
        }
        void* args[] = {(void*)&h, (void*)&weight, (void*)&bias, (void*)&src, (void*)&dst,
                        (void*)&rel, (void*)&E, (void*)&meta, (void*)&wb, (void*)&hb,
                        (void*)&msg, (void*)&out};
        hipError_t le = hipLaunchCooperativeKernel((const void*)fused_kernel,
                                                   dim3(grid), dim3(256), args, 0, stream);
        if (le == hipSuccess) return;

        // Cooperative rejected -> identical phases as 4 plain dispatches.
        k_init<<<2048, 256, 0, stream>>>(meta, wb, hb, weight, h);
        k_scatter<<<(E + 255) / 256, 256, 0, stream>>>(src, dst, rel, E, meta);
        k_edge<<<NGS / 4, 256, 0, stream>>>(hb, wb, meta, msg);
        k_agg<<<(NN + 3) / 4, 256, 0, stream>>>(msg, meta, bias, out);
    } else {
        hipMemsetAsync(out, 0, (size_t)out_size * sizeof(float), stream);
        fb_edge_kernel<<<(E + 3) / 4, 256, 0, stream>>>(h, weight, src, dst, rel, out, E);
        fb_finalize_kernel<<<(out_size + 255) / 256, 256, 0, stream>>>(out, bias, out_size);
    }
}

// Round 14
// 56.984 us; speedup vs baseline: 6.7220x; 6.7220x over previous
//
#include <hip/hip_runtime.h>

#define NN 50000
#define DD 50
#define RR 64
#define BINS 2048                   // (rel, e&31) sub-bins
#define CAP 128                     // slots per bin (mean ~49; 11.5-sigma margin)
#define CAPN 24                     // per-node perm slots (in-degree ~Poisson(2))

// meta ints: bin cursors | node cursors | perm | int2 slots
#define BINCUR_OFF 0                                   // 2048
#define DCUR_OFF   2048                                // 50000
#define PERM_OFF   52048                               // 50000*24 = 1200000
#define SD_OFF     1252048                             // 2*BINS*CAP = 524288
#define META_INTS  1776336
#define WB_BYTE    ((size_t)META_INTS * 4)             // 7,105,344
#define HB_BYTE    ((WB_BYTE + (size_t)RR * 64 * 64 * 2 + 127) & ~(size_t)127)  // 128B-aligned
#define MSG_BYTE   (HB_BYTE + (size_t)NN * 64 * 2)
#define WS_NEED    (MSG_BYTE + (size_t)BINS * CAP * 64 * 2)   // ~47.6 MB

typedef __attribute__((ext_vector_type(8))) short bf16x8;
typedef __attribute__((ext_vector_type(4))) float f32x4;

__device__ __forceinline__ unsigned short f2b(float f) {   // f32 -> bf16 RNE
    unsigned u = __float_as_uint(f);
    u = (u + 0x7fffu + ((u >> 16) & 1u)) >> 16;
    return (unsigned short)u;
}

// P0: zero cursors; wb[r][n][k] = bf16 W^T (64x64 zero-padded, COALESCED writes);
//     hb[n][64] = bf16 h rows padded to 64 cols (one 128B line per row).
__global__ __launch_bounds__(256) void k_init(int* __restrict__ meta,
        unsigned short* __restrict__ wb, unsigned short* __restrict__ hb,
        const float* __restrict__ w, const float* __restrict__ h) {
    int tid = blockIdx.x * 256 + threadIdx.x;
    int nth = gridDim.x * 256;
    for (int j = tid; j < BINS + NN; j += nth) meta[j] = 0;
    for (int j = tid; j < RR * 64 * 64; j += nth) {
        int r = j >> 12, n = (j >> 6) & 63, d = j & 63;   // consecutive tid -> consecutive d
        float v = (n < DD && d < DD) ? w[r * (DD * DD) + d * DD + n] : 0.f;
        wb[j] = f2b(v);                                   // coalesced 2B writes
    }
    for (int j = tid; j < NN * 32; j += nth) {
        int n = j >> 5, cp = j & 31;
        unsigned pack = 0;
        if (cp < 25) {
            float2 q = *(const float2*)(h + (size_t)n * DD + cp * 2);
            pack = (unsigned)f2b(q.x) | ((unsigned)f2b(q.y) << 16);
        }
        *(unsigned*)(hb + ((size_t)n << 6) + (cp << 1)) = pack;
    }
}

// P1: scatter edges into (rel, e&31) bins (2048 cursors, ~49-deep contention).
__global__ void k_scatter(const int* __restrict__ src, const int* __restrict__ dst,
                          const int* __restrict__ rel, int E, int* __restrict__ meta) {
    int e = blockIdx.x * blockDim.x + threadIdx.x;
    if (e >= E) return;
    int sb = (rel[e] << 5) | (e & 31);
    int p = atomicAdd(&meta[BINCUR_OFF + sb], 1);
    if (p < CAP)                                 // never fires at 11.5 sigma
        ((int2*)(meta + SD_OFF))[sb * CAP + p] = make_int2(src[e], dst[e]);
}

// P2: one wave = quarter-bin = 32 edges (2 MFMA groups), single relation.
// All loads issued up front (cnt -> 32 slots coalesced -> 4 A-gathers + 8
// B-frags), B-frags reused across both groups, then 16 MFMAs + msg stores.
__global__ __launch_bounds__(256) void k_edge(const unsigned short* __restrict__ hb,
        const unsigned short* __restrict__ wb, int* __restrict__ meta,
        unsigned short* __restrict__ msg) {
    int lane = threadIdx.x & 63;
    int wv = (blockIdx.x << 2) + (threadIdx.x >> 6);     // 0..8191
    int b = wv >> 2, qt = wv & 3;
    int cnt = __builtin_amdgcn_readfirstlane(meta[BINCUR_OFF + b]);
    if (cnt > CAP) cnt = CAP;
    int avail = cnt - (qt << 5);
    if (avail <= 0) return;
    if (avail > 32) avail = 32;
    int r = b >> 5;
    int slotbase = (b << 7) + (qt << 5);

    int2 sd = make_int2(0, -1);                           // sanitized defaults
    if (lane < avail) sd = ((const int2*)(meta + SD_OFF))[slotbase + lane];
    if (lane < avail) {                                   // perm append
        int pos = atomicAdd(&meta[DCUR_OFF + sd.y], 1);
        if (pos < CAPN)                                   // P ~ 1e-18, guard anyway
            meta[PERM_OFF + sd.y * CAPN + pos] = slotbase + lane;
    }
    int ch = lane >> 4, col0 = lane & 15;

    // A-frags for both groups (sv sanitized to 0 for invalid lanes -> safe)
    int sv0 = __shfl(sd.x, col0);
    int sv1 = __shfl(sd.x, 16 + col0);
    const unsigned short* h0 = hb + ((size_t)sv0 << 6) + (ch << 3);
    const unsigned short* h1 = hb + ((size_t)sv1 << 6) + (ch << 3);
    bf16x8 a00 = *(const bf16x8*)h0;
    bf16x8 a01 = *(const bf16x8*)(h0 + 32);
    bf16x8 a10 = *(const bf16x8*)h1;
    bf16x8 a11 = *(const bf16x8*)(h1 + 32);

    // B-frags once (relation-uniform), reused by both groups
    const unsigned short* wr = wb + ((size_t)r << 12) + (col0 << 6) + (ch << 3);
    bf16x8 bb0[4], bb1[4];
    #pragma unroll
    for (int t = 0; t < 4; ++t) {
        bb0[t] = *(const bf16x8*)(wr + t * 1024);
        bb1[t] = *(const bf16x8*)(wr + t * 1024 + 32);
    }

    {   // group 0: rows slotbase .. +15
        f32x4 c[4];
        #pragma unroll
        for (int t = 0; t < 4; ++t) {
            c[t] = (f32x4){0.f, 0.f, 0.f, 0.f};
            c[t] = __builtin_amdgcn_mfma_f32_16x16x32_bf16(a00, bb0[t], c[t], 0, 0, 0);
            c[t] = __builtin_amdgcn_mfma_f32_16x16x32_bf16(a01, bb1[t], c[t], 0, 0, 0);
        }
        // C layout (m89): col = t*16+col0, row = ch*4+q
        unsigned short* mb = msg + (size_t)(slotbase + (ch << 2)) * 64;
        #pragma unroll
        for (int q = 0; q < 4; ++q)
            #pragma unroll
            for (int t = 0; t < 4; ++t)
                mb[q * 64 + t * 16 + col0] = f2b(c[t][q]);
    }
    if (avail > 16) {   // group 1: rows slotbase+16 .. +31
        f32x4 c[4];
        #pragma unroll
        for (int t = 0; t < 4; ++t) {
            c[t] = (f32x4){0.f, 0.f, 0.f, 0.f};
            c[t] = __builtin_amdgcn_mfma_f32_16x16x32_bf16(a10, bb0[t], c[t], 0, 0, 0);
            c[t] = __builtin_amdgcn_mfma_f32_16x16x32_bf16(a11, bb1[t], c[t], 0, 0, 0);
        }
        unsigned short* mb = msg + (size_t)(slotbase + 16 + (ch << 2)) * 64;
        #pragma unroll
        for (int q = 0; q < 4; ++q)
            #pragma unroll
            for (int t = 0; t < 4; ++t)
                mb[q * 64 + t * 16 + col0] = f2b(c[t][q]);
    }
}

// P3: one wave per node: cnt + perm via batched int4 prefetch, independent
// bf16 msg-row reads, +bias, relu, store (every output row written once).
__global__ __launch_bounds__(256) void k_agg(const unsigned short* __restrict__ msg,
        const int* __restrict__ meta, const float* __restrict__ bias,
        float* __restrict__ out) {
    int lane = threadIdx.x & 63;
    int n = (blockIdx.x << 2) + (threadIdx.x >> 6);
    if (n >= NN) return;
    int cnt = __builtin_amdgcn_readfirstlane(meta[DCUR_OFF + n]);
    if (cnt > CAPN) cnt = CAPN;
    float v = 0.f;
    const int4* pp = (const int4*)(meta + PERM_OFF + n * CAPN);
    int4 P0 = pp[0], P1 = pp[1];                  // covers deg<=8 (99.98%)
    int pj[8] = {P0.x, P0.y, P0.z, P0.w, P1.x, P1.y, P1.z, P1.w};
    #pragma unroll
    for (int j = 0; j < 8; ++j) {
        if (j < cnt) {
            unsigned short u = msg[(size_t)pj[j] * 64 + lane];
            v += __uint_as_float((unsigned)u << 16);
        }
    }
    #pragma unroll 1
    for (int j = 8; j < cnt; ++j) {               // rare tail
        int p = meta[PERM_OFF + n * CAPN + j];
        unsigned short u = msg[(size_t)p * 64 + lane];
        v += __uint_as_float((unsigned)u << 16);
    }
    if (lane < DD) {
        float o = v + bias[lane];
        out[(size_t)n * DD + lane] = o > 0.f ? o : 0.f;
    }
}

// ---------- tiny-ws fallback: round-1 style atomics ----------
__global__ void fb_edge_kernel(const float* __restrict__ h, const float* __restrict__ weight,
                               const int* __restrict__ src_idx, const int* __restrict__ dst_idx,
                               const int* __restrict__ rel_type, float* __restrict__ acc, int E) {
    int wave = (int)((blockIdx.x * blockDim.x + threadIdx.x) >> 6);
    int lane = threadIdx.x & 63;
    if (wave >= E) return;
    int s = src_idx[wave], r = rel_type[wave], dn = dst_idx[wave];
    const float* hs = h + (size_t)s * DD;
    const float* W  = weight + (size_t)r * DD * DD;
    if (lane < DD) {
        float m = 0.f;
        for (int d = 0; d < DD; ++d) m = fmaf(hs[d], W[d * DD + lane], m);
        atomicAdd(&acc[(size_t)dn * DD + lane], m);
    }
}
__global__ void fb_finalize_kernel(float* __restrict__ out, const float* __restrict__ bias, int total) {
    int i = blockIdx.x * blockDim.x + threadIdx.x;
    if (i < total) {
        float v = out[i] + bias[i % DD];
        out[i] = v > 0.f ? v : 0.f;
    }
}

extern "C" void kernel_launch(void* const* d_in, const int* in_sizes, int n_in,
                              void* d_out, int out_size, void* d_ws, size_t ws_size,
                              hipStream_t stream) {
    const float* h      = (const float*)d_in[0];
    const float* weight = (const float*)d_in[1];
    const float* bias   = (const float*)d_in[2];
    const int*   src    = (const int*)d_in[3];
    const int*   dst    = (const int*)d_in[4];
    const int*   rel    = (const int*)d_in[5];
    float* out = (float*)d_out;
    int E = in_sizes[3];

    if (ws_size >= WS_NEED) {
        int* meta = (int*)d_ws;
        unsigned short* wb  = (unsigned short*)((char*)d_ws + WB_BYTE);
        unsigned short* hb  = (unsigned short*)((char*)d_ws + HB_BYTE);
        unsigned short* msg = (unsigned short*)((char*)d_ws + MSG_BYTE);

        k_init<<<2048, 256, 0, stream>>>(meta, wb, hb, weight, h);
        k_scatter<<<(E + 255) / 256, 256, 0, stream>>>(src, dst, rel, E, meta);
        k_edge<<<2048, 256, 0, stream>>>(hb, wb, meta, msg);
        k_agg<<<(NN + 3) / 4, 256, 0, stream>>>(msg, meta, bias, out);
    } else {
        hipMemsetAsync(out, 0, (size_t)out_size * sizeof(float), stream);
        fb_edge_kernel<<<(E + 3) / 4, 256, 0, stream>>>(h, weight, src, dst, rel, out, E);
        fb_finalize_kernel<<<(out_size + 255) / 256, 256, 0, stream>>>(out, bias, out_size);
    }
}